// Round 1
// baseline (3968.407 us; speedup 1.0000x reference)
//
#include <hip/hip_runtime.h>

typedef _Float16 f16x8 __attribute__((ext_vector_type(8)));
typedef float    f32x4 __attribute__((ext_vector_type(4)));
typedef unsigned long long u64;
typedef u64 u64x2 __attribute__((ext_vector_type(2)));

constexpr int BATCH = 1024;
constexpr int HDIM  = 512;
constexpr int TENC  = 512;
constexpr int PRED  = 48;
constexpr int STEPS = TENC + PRED - 1;   // 559 cell steps; loop runs 560 (last = fc only)
constexpr int NG    = 64;                // groups (16 batches each)
constexpr int GB    = 16;                // batches per group = one MFMA m-tile
constexpr int UBU   = 64;                // units per block (4 waves x 16)
constexpr int HB_OFF = 32768;
constexpr int XCC_TAB_OFF = 1024;        // int index into ws (byte 4096), zeroed by init

// In-band tag (R7/R8-proven): each 4B dword of stored h carries step tag at
// bit0/bit16. h_t in buffer t&1, tag t&3; skew <= 1 step (data dependency)
// => 2-bit tag + ping-pong is ABA-safe. Stores remain LLC write-through
// (sc0 sc1). NEW (R11): work is relabeled so each 8-block cluster maps to one
// XCD under the bid%8 round-robin heuristic; XCC_IDs are published+verified,
// and verified-local clusters use sc0-only (XCD L2) loads. Sticky escalation
// back to sc0 sc1 loads guarantees forward progress in every scenario.
constexpr u64 TAG_MASK = 0x0001000100010001ull;
__device__ __forceinline__ u64 tag_of(int t) {
  return ((u64)(t & 1) | ((u64)((t >> 1) & 1) << 16)) * 0x0000000100000001ull;
}

__global__ void init_kernel(int* wsi) {
  int idx = blockIdx.x * blockDim.x + threadIdx.x;
  int stride = gridDim.x * blockDim.x;
  const int nws = (HB_OFF + BATCH * HDIM * 2) / 4;  // hbuf[0] = h_0 = 0 (tag 00)
  for (int i = idx; i < nws; i += stride) wsi[i] = 0;
  // hbuf[1] stays 0xAA poison -> tag-invalid until written
}

static __device__ __forceinline__ f16x8 load16_llc(const _Float16* p) {
  f16x8 v;
  asm volatile("global_load_dwordx4 %0, %1, off sc0 sc1"
               : "=v"(v) : "v"((u64)p) : "memory");
  return v;
}
static __device__ __forceinline__ f16x8 load16_l2(const _Float16* p) {
  f16x8 v;   // XCD-local L2 scope: bypass L1 (sc0), hit shared L2
  asm volatile("global_load_dwordx4 %0, %1, off sc0"
               : "=v"(v) : "v"((u64)p) : "memory");
  return v;
}
static __device__ __forceinline__ float loadx(const float* p) {
  float v;   // plain cached load via asm so compiler never vmcnt(0)-drains our prefetch
  asm volatile("global_load_dword %0, %1, off"
               : "=v"(v) : "v"((u64)p) : "memory");
  return v;
}

// Two interleaved 16-batch recurrences per block (A: grp=role>>3, B: grp+32),
// same 64-unit weight tile for both. Phase pipeline: B's remote loads fly
// during A's GEMM+epilogue and vice versa. Role relabeling: blocks with equal
// bid%8 (same XCD under round-robin dispatch) form the 8-block exchange
// cluster, so verified-local clusters exchange through the XCD's L2.
__global__ __launch_bounds__(256, 1) void lstm_persist(
    const float* __restrict__ x,
    const float* __restrict__ w_ih,
    const float* __restrict__ w_hh,
    const float* __restrict__ b_ih,
    const float* __restrict__ b_hh,
    const float* __restrict__ w_fc,
    const float* __restrict__ b_fc,
    float* __restrict__ out,          // [1024][48] fp32, plain stores
    _Float16* __restrict__ hbuf,      // [2][1024][512] fp16 ping-pong, tagged
    int* __restrict__ wsi)            // workspace base (xcc publish table)
{
  const int bid0 = blockIdx.x;
  // bijection: cluster peers = {x, x+8, ..., x+56} for x = bid0&7
  const int role = ((bid0 & 7) << 5) | (bid0 >> 3);
  const int gA   = role >> 3;         // group A (0..31); B = gA+32
  const int ub   = role & 7;
  const int tid  = threadIdx.x;
  const int wid  = tid >> 6;
  const int lane = tid & 63;
  const int quad = lane >> 4;
  const int lcol = lane & 15;
  const int bA0  = gA * GB;
  const int bB0  = bA0 + NG / 2 * GB; // = bA0 + 512
  const int myu  = ub * UBU + wid * 16 + lcol;
  const int uoff = ub * UBU + wid * 16 + (lcol & ~3);

  __shared__ __align__(16) _Float16 hsA[GB][520];    // 16.6 KB
  __shared__ __align__(16) _Float16 hsB[GB][520];    // 16.6 KB
  __shared__ __align__(16) _Float16 wz[520];         // fp16 w_fc + zero pad
  __shared__ int s_local;

  // ---- publish my XCC_ID for this role, then verify cluster co-location ----
  if (tid == 0) {
    unsigned xcc;
    asm volatile("s_getreg_b32 %0, hwreg(HW_REG_XCC_ID)" : "=s"(xcc));
    int* tab = wsi + XCC_TAB_OFF;
    __hip_atomic_store(&tab[role], (int)(8u | (xcc & 7u)), __ATOMIC_RELAXED,
                       __HIP_MEMORY_SCOPE_AGENT);
    const int base = gA << 3;
    int v0 = 0, ok = 1;
    for (int p = 0; p < 8; ++p) {
      int v;
      for (;;) {
        v = __hip_atomic_load(&tab[base + p], __ATOMIC_RELAXED,
                              __HIP_MEMORY_SCOPE_AGENT);
        if (v != 0) break;
        __builtin_amdgcn_s_sleep(8);
      }
      if (p == 0) v0 = v;
      else if (v != v0) ok = 0;
    }
    s_local = ok;
  }

  for (int k = tid; k < 512; k += 256) wz[k] = (_Float16)w_fc[k];
  if (tid < 8) wz[512 + tid] = (_Float16)0.f;

  // ---- full-K weight B-frags (n=lcol, k=kc*32+quad*8+j) ----
  f16x8 wf[4][16];
  float wih[4], bias[4];
#pragma unroll
  for (int nt = 0; nt < 4; ++nt) {
    const int j = nt * HDIM + myu;
    wih[nt]  = w_ih[j];
    bias[nt] = b_ih[j] + b_hh[j];
#pragma unroll
    for (int kc = 0; kc < 16; ++kc) {
      const float* s = w_hh + (size_t)j * HDIM + kc * 32 + quad * 8;
      f16x8 v;
#pragma unroll
      for (int i = 0; i < 8; ++i) v[i] = (_Float16)s[i];
      wf[nt][kc] = v;
    }
  }
  const float bfc = b_fc[0];

  __syncthreads();
  const bool local = (s_local != 0);
  bool esc = false;   // sticky per-thread escalation back to LLC-scope loads

  float cstA[4], cstB[4];
#pragma unroll
  for (int r = 0; r < 4; ++r) { cstA[r] = 0.f; cstB[r] = 0.f; }

  // staging: 16 rows x 512 units = 1024 16B-chunks; thread covers 4
  // (c = i*256+tid: row=c>>6, col16=c&63). Includes own slice (own
  // store->load via LLC/L2 is same-thread ordered; R7-verified).
  f16x8 tA[4], tB[4];

  auto issue4 = [&](f16x8* tr, const _Float16* base) {
    const bool llc = (!local) | esc;
#pragma unroll
    for (int i = 0; i < 4; ++i) {
      const int c = i * 256 + tid;
      const _Float16* p = base + (size_t)(c >> 6) * HDIM + (c & 63) * 8;
      tr[i] = llc ? load16_llc(p) : load16_l2(p);
    }
  };
  auto validate4 = [&](f16x8* tr, const _Float16* base, u64 expect) {
    unsigned stale = 0xf;
    int rounds = 0;
    for (;;) {
      unsigned ns = 0;
#pragma unroll
      for (int i = 0; i < 4; ++i)
        if (stale & (1u << i)) {
          u64x2 w2 = __builtin_bit_cast(u64x2, tr[i]);
          if (((w2[0] & TAG_MASK) != expect) || ((w2[1] & TAG_MASK) != expect))
            ns |= 1u << i;
        }
      if (ns == 0) break;
      if (++rounds > 64) esc = true;   // stale-L2 scenario: fall back for good
      __builtin_amdgcn_s_sleep(1);
      const bool llc = (!local) | esc;
#pragma unroll
      for (int i = 0; i < 4; ++i)
        if (ns & (1u << i)) {
          const int c = i * 256 + tid;
          const _Float16* p = base + (size_t)(c >> 6) * HDIM + (c & 63) * 8;
          tr[i] = llc ? load16_llc(p) : load16_l2(p);
        }
      asm volatile("s_waitcnt vmcnt(0)" ::: "memory");
      stale = ns;
    }
  };
  auto stage4 = [&](f16x8* tr, _Float16 (*hsp)[520]) {
#pragma unroll
    for (int i = 0; i < 4; ++i) {
      const int c = i * 256 + tid;
      *reinterpret_cast<f16x8*>(&hsp[c >> 6][(c & 63) * 8]) = tr[i];
    }
  };
  auto gemm = [&](const _Float16 (*hsp)[520], f32x4* acc, f32x4& accF, bool dec) {
#pragma unroll
    for (int kc = 0; kc < 16; ++kc) {
      const f16x8 a = *reinterpret_cast<const f16x8*>(&hsp[lcol][kc * 32 + quad * 8]);
#pragma unroll
      for (int nt = 0; nt < 4; ++nt)
        acc[nt] = __builtin_amdgcn_mfma_f32_16x16x32_f16(a, wf[nt][kc], acc[nt], 0, 0, 0);
      if (dec) {   // fc: B row 0 = w_fc, rows 1..15 = 0 (zero-pad broadcast)
        const f16x8 wv = *reinterpret_cast<const f16x8*>(
            &wz[(lcol == 0) ? (kc * 32 + quad * 8) : 512]);
        accF = __builtin_amdgcn_mfma_f32_16x16x32_f16(a, wv, accF, 0, 0, 0);
      }
    }
  };
  auto tail = [&](f32x4* acc, f32x4& accF, float* xv, float* cstv,
                  int bX0, int t, _Float16* hnxt, bool dec) {
    if (dec) {   // xt = fc(h_t), redundant per block; preds stored by ub0/w0
#pragma unroll
      for (int r = 0; r < 4; ++r) xv[r] = __shfl(accF[r], quad * 16) + bfc;
      if (ub == 0 && wid == 0 && lcol == 0) {
        const int p = t - TENC;
#pragma unroll
        for (int r = 0; r < 4; ++r)
          out[(size_t)(bX0 + quad * 4 + r) * PRED + p] = accF[r] + bfc;
      }
    }
    if (t < STEPS) {
      const u64 tagnew = tag_of(t + 1);
#pragma unroll
      for (int r = 0; r < 4; ++r) {
        const float xt = xv[r];
        const float gi = acc[0][r] + xt * wih[0] + bias[0];
        const float gf = acc[1][r] + xt * wih[1] + bias[1];
        const float gg = acc[2][r] + xt * wih[2] + bias[2];
        const float go = acc[3][r] + xt * wih[3] + bias[3];
        const float si = 1.f / (1.f + __expf(-gi));
        const float sf = 1.f / (1.f + __expf(-gf));
        const float so = 1.f / (1.f + __expf(-go));
        const float tg = 1.f - 2.f / (1.f + __expf(2.f * gg));
        const float cn = sf * cstv[r] + si * tg;
        cstv[r] = cn;
        const float tc = 1.f - 2.f / (1.f + __expf(2.f * cn));
        const float hn = so * tc;

        const unsigned short hb = __builtin_bit_cast(unsigned short, (_Float16)hn);
        const unsigned v0  = hb;
        const unsigned o0  = (unsigned)__shfl_xor((int)v0, 1);
        const unsigned p01 = (lcol & 1) ? ((v0 << 16) | o0) : ((o0 << 16) | v0);
        const unsigned q   = (unsigned)__shfl_xor((int)p01, 2);
        u64 p4 = (lcol & 2) ? (((u64)p01 << 32) | (u64)q)
                            : (((u64)q << 32) | (u64)p01);
        p4 = (p4 & ~TAG_MASK) | tagnew;
        if ((lcol & 3) == r) {
          _Float16* dst = hnxt + (size_t)(bX0 + quad * 4 + r) * HDIM + uoff;
          __hip_atomic_store((u64*)dst, p4, __ATOMIC_RELAXED,
                             __HIP_MEMORY_SCOPE_AGENT);
        }
      }
    }
  };

  issue4(tA, hbuf + (size_t)bA0 * HDIM);   // prologue: A(0) in flight

  for (int t = 0; t <= STEPS; ++t) {
    const _Float16* hcur = hbuf + (size_t)(t & 1) * BATCH * HDIM;
    _Float16*       hnxt = hbuf + (size_t)((t + 1) & 1) * BATCH * HDIM;
    const u64 expect = tag_of(t);
    const bool dec = (t >= TENC);

    // ================= phase A =================
    float xA[4];
    if (!dec) {
#pragma unroll
      for (int r = 0; r < 4; ++r)
        xA[r] = loadx(x + (size_t)(bA0 + quad * 4 + r) * TENC + t);
    }
    asm volatile("s_waitcnt vmcnt(0)" ::: "memory");   // tA (+xA) landed
    validate4(tA, hcur + (size_t)bA0 * HDIM, expect);
    stage4(tA, hsA);
    __syncthreads();
    issue4(tB, hcur + (size_t)bB0 * HDIM);             // B(t) flies during A compute

    f32x4 accA[4], accFA;
#pragma unroll
    for (int nt = 0; nt < 4; ++nt) accA[nt] = (f32x4){0.f, 0.f, 0.f, 0.f};
    accFA = (f32x4){0.f, 0.f, 0.f, 0.f};
    gemm(hsA, accA, accFA, dec);
    tail(accA, accFA, xA, cstA, bA0, t, hnxt, dec);

    // ================= phase B =================
    float xB[4];
    if (!dec) {
#pragma unroll
      for (int r = 0; r < 4; ++r)
        xB[r] = loadx(x + (size_t)(bB0 + quad * 4 + r) * TENC + t);
    }
    asm volatile("s_waitcnt vmcnt(0)" ::: "memory");   // tB (+xB, A-publish) landed
    validate4(tB, hcur + (size_t)bB0 * HDIM, expect);
    stage4(tB, hsB);
    __syncthreads();
    if (t < STEPS)
      issue4(tA, hnxt + (size_t)bA0 * HDIM);           // A(t+1) flies during B compute

    f32x4 accB[4], accFB;
#pragma unroll
    for (int nt = 0; nt < 4; ++nt) accB[nt] = (f32x4){0.f, 0.f, 0.f, 0.f};
    accFB = (f32x4){0.f, 0.f, 0.f, 0.f};
    gemm(hsB, accB, accFB, dec);
    tail(accB, accFB, xB, cstB, bB0, t, hnxt, dec);
  }
}

extern "C" void kernel_launch(void* const* d_in, const int* in_sizes, int n_in,
                              void* d_out, int out_size, void* d_ws, size_t ws_size,
                              hipStream_t stream) {
  const float* x    = (const float*)d_in[0];
  const float* w_ih = (const float*)d_in[1];
  const float* w_hh = (const float*)d_in[2];
  const float* b_ih = (const float*)d_in[3];
  const float* b_hh = (const float*)d_in[4];
  const float* w_fc = (const float*)d_in[5];
  const float* b_fc = (const float*)d_in[6];
  float* out = (float*)d_out;
  _Float16* hbuf = (_Float16*)((char*)d_ws + HB_OFF);

  hipLaunchKernelGGL(init_kernel, dim3(256), dim3(256), 0, stream, (int*)d_ws);
  hipLaunchKernelGGL(lstm_persist, dim3(256), dim3(256), 0, stream,
                     x, w_ih, w_hh, b_ih, b_hh, w_fc, b_fc, out, hbuf, (int*)d_ws);
}

// Round 5
// 3448.555 us; speedup vs baseline: 1.1507x; 1.1507x over previous
//
#include <hip/hip_runtime.h>

typedef _Float16 f16x8 __attribute__((ext_vector_type(8)));
typedef float    f32x4 __attribute__((ext_vector_type(4)));
typedef unsigned long long u64;
typedef u64 u64x2 __attribute__((ext_vector_type(2)));

constexpr int BATCH = 1024;
constexpr int HDIM  = 512;
constexpr int TENC  = 512;
constexpr int PRED  = 48;
constexpr int STEPS = TENC + PRED - 1;   // 559 cell steps; loop runs 560 (last = fc only)
constexpr int NG    = 64;                // groups (16 batches each)
constexpr int GB    = 16;                // batches per group = one MFMA m-tile
constexpr int UBU   = 64;                // units per block (4 waves x 16)
constexpr int HB_OFF = 32768;

// In-band tag (R7/R8-proven): each 4B dword of stored h carries step tag at
// bit0/bit16. h_t in buffer t&1, tag t&3; skew <= 1 step (data dependency)
// => 2-bit tag + ping-pong is ABA-safe. LLC scope only.
// R15 = R14 with the s_sleep constant-arg compile fix:
// (a) canary polling - retry rounds poll 4B/chunk instead of re-loading
// 64B/thread, cutting the load-storm that contends with the producer's
// write-through stores at the shared cache banks; full 16B reload happens
// only once the canary tag flips. Termination identical to proven hammer.
// (b) x loads prefetched one phase early (removes ~900cy exposed HBM
// latency at each phase start).
constexpr u64 TAG_MASK = 0x0001000100010001ull;
__device__ __forceinline__ u64 tag_of(int t) {
  return ((u64)(t & 1) | ((u64)((t >> 1) & 1) << 16)) * 0x0000000100000001ull;
}

__global__ void init_kernel(int* wsi) {
  int idx = blockIdx.x * blockDim.x + threadIdx.x;
  int stride = gridDim.x * blockDim.x;
  const int nws = (HB_OFF + BATCH * HDIM * 2) / 4;  // hbuf[0] = h_0 = 0 (tag 00)
  for (int i = idx; i < nws; i += stride) wsi[i] = 0;
  // hbuf[1] stays 0xAA poison -> tag-invalid until written
}

static __device__ __forceinline__ f16x8 load16_llc(const _Float16* p) {
  f16x8 v;
  asm volatile("global_load_dwordx4 %0, %1, off sc0 sc1"
               : "=v"(v) : "v"((u64)p) : "memory");
  return v;
}
static __device__ __forceinline__ unsigned loadc_llc(const void* p) {
  unsigned v;   // 4B canary: in-band tag probe, 1/4 the traffic of a chunk
  asm volatile("global_load_dword %0, %1, off sc0 sc1"
               : "=v"(v) : "v"((u64)p) : "memory");
  return v;
}
static __device__ __forceinline__ float loadx(const float* p) {
  float v;   // plain cached load via asm so compiler never vmcnt(0)-drains our prefetch
  asm volatile("global_load_dword %0, %1, off"
               : "=v"(v) : "v"((u64)p) : "memory");
  return v;
}
// s_sleep needs a literal operand: 4-step constant backoff ladder.
static __device__ __forceinline__ void sleep_bk(int stage) {
  if (stage == 0)      __builtin_amdgcn_s_sleep(1);
  else if (stage == 1) __builtin_amdgcn_s_sleep(2);
  else if (stage == 2) __builtin_amdgcn_s_sleep(4);
  else                 __builtin_amdgcn_s_sleep(8);
}

// Two interleaved 16-batch recurrences per block (A: grp=bid>>3, B: grp+32),
// same 64-unit weight tile for both. Phase pipeline: B's remote loads fly
// during A's GEMM+epilogue and vice versa -> the LLC visibility round trip
// is hidden behind the other group's compute. Protocol = R8 verbatim.
__global__ __launch_bounds__(256, 1) void lstm_persist(
    const float* __restrict__ x,
    const float* __restrict__ w_ih,
    const float* __restrict__ w_hh,
    const float* __restrict__ b_ih,
    const float* __restrict__ b_hh,
    const float* __restrict__ w_fc,
    const float* __restrict__ b_fc,
    float* __restrict__ out,          // [1024][48] fp32, plain stores
    _Float16* __restrict__ hbuf)      // [2][1024][512] fp16 ping-pong, tagged
{
  const int bid  = blockIdx.x;
  const int gA   = bid >> 3;          // group A (0..31); B = gA+32
  const int ub   = bid & 7;
  const int tid  = threadIdx.x;
  const int wid  = tid >> 6;
  const int lane = tid & 63;
  const int quad = lane >> 4;
  const int lcol = lane & 15;
  const int bA0  = gA * GB;
  const int bB0  = bA0 + NG / 2 * GB; // = bA0 + 512
  const int myu  = ub * UBU + wid * 16 + lcol;
  const int uoff = ub * UBU + wid * 16 + (lcol & ~3);

  __shared__ __align__(16) _Float16 hsA[GB][520];    // 16.6 KB
  __shared__ __align__(16) _Float16 hsB[GB][520];    // 16.6 KB
  __shared__ __align__(16) _Float16 wz[520];         // fp16 w_fc + zero pad

  for (int k = tid; k < 512; k += 256) wz[k] = (_Float16)w_fc[k];
  if (tid < 8) wz[512 + tid] = (_Float16)0.f;

  // ---- full-K weight B-frags (n=lcol, k=kc*32+quad*8+j) ----
  f16x8 wf[4][16];
  float wih[4], bias[4];
#pragma unroll
  for (int nt = 0; nt < 4; ++nt) {
    const int j = nt * HDIM + myu;
    wih[nt]  = w_ih[j];
    bias[nt] = b_ih[j] + b_hh[j];
#pragma unroll
    for (int kc = 0; kc < 16; ++kc) {
      const float* s = w_hh + (size_t)j * HDIM + kc * 32 + quad * 8;
      f16x8 v;
#pragma unroll
      for (int i = 0; i < 8; ++i) v[i] = (_Float16)s[i];
      wf[nt][kc] = v;
    }
  }
  const float bfc = b_fc[0];

  float cstA[4], cstB[4];
#pragma unroll
  for (int r = 0; r < 4; ++r) { cstA[r] = 0.f; cstB[r] = 0.f; }

  // staging: 16 rows x 512 units = 1024 16B-chunks; thread covers 4
  // (c = i*256+tid: row=c>>6, col16=c&63). Includes own slice (own
  // store->load via LLC is same-thread ordered; R7-verified).
  f16x8 tA[4], tB[4];
  float xA[4], xB[4];

  auto issue4 = [&](f16x8* tr, const _Float16* base) {
#pragma unroll
    for (int i = 0; i < 4; ++i) {
      const int c = i * 256 + tid;
      tr[i] = load16_llc(base + (size_t)(c >> 6) * HDIM + (c & 63) * 8);
    }
  };
  // R14 canary validate: initial full-tag check on the prefetched data; on
  // staleness, poll only the first dword of each stale chunk (4B) with
  // constant-ladder sleep backoff; full 16B reload only once the canary tag
  // flips; full tag re-check clears the chunk (second u64 half may land
  // later -> loop continues, same termination property as the old hammer).
  auto validate4 = [&](f16x8* tr, const _Float16* base, u64 expect) {
    const unsigned exp32 = (unsigned)expect & 0x00010001u;
    unsigned stale = 0;
#pragma unroll
    for (int i = 0; i < 4; ++i) {
      u64x2 w2 = __builtin_bit_cast(u64x2, tr[i]);
      if (((w2[0] & TAG_MASK) != expect) || ((w2[1] & TAG_MASK) != expect))
        stale |= 1u << i;
    }
    int slp = 0;
    while (stale) {
      sleep_bk(slp);
      if (slp < 3) ++slp;
      unsigned cv[4];
#pragma unroll
      for (int i = 0; i < 4; ++i)
        if (stale & (1u << i)) {
          const int c = i * 256 + tid;
          cv[i] = loadc_llc(base + (size_t)(c >> 6) * HDIM + (c & 63) * 8);
        }
      asm volatile("s_waitcnt vmcnt(0)" ::: "memory");
      unsigned rdy = 0;
#pragma unroll
      for (int i = 0; i < 4; ++i)
        if ((stale & (1u << i)) && ((cv[i] & 0x00010001u) == exp32))
          rdy |= 1u << i;
      if (!rdy) continue;
#pragma unroll
      for (int i = 0; i < 4; ++i)
        if (rdy & (1u << i)) {
          const int c = i * 256 + tid;
          tr[i] = load16_llc(base + (size_t)(c >> 6) * HDIM + (c & 63) * 8);
        }
      asm volatile("s_waitcnt vmcnt(0)" ::: "memory");
#pragma unroll
      for (int i = 0; i < 4; ++i)
        if (rdy & (1u << i)) {
          u64x2 w2 = __builtin_bit_cast(u64x2, tr[i]);
          if (((w2[0] & TAG_MASK) == expect) && ((w2[1] & TAG_MASK) == expect))
            stale &= ~(1u << i);
        }
    }
  };
  auto stage4 = [&](f16x8* tr, _Float16 (*hsp)[520]) {
#pragma unroll
    for (int i = 0; i < 4; ++i) {
      const int c = i * 256 + tid;
      *reinterpret_cast<f16x8*>(&hsp[c >> 6][(c & 63) * 8]) = tr[i];
    }
  };
  auto gemm = [&](const _Float16 (*hsp)[520], f32x4* acc, f32x4& accF, bool dec) {
#pragma unroll
    for (int kc = 0; kc < 16; ++kc) {
      const f16x8 a = *reinterpret_cast<const f16x8*>(&hsp[lcol][kc * 32 + quad * 8]);
#pragma unroll
      for (int nt = 0; nt < 4; ++nt)
        acc[nt] = __builtin_amdgcn_mfma_f32_16x16x32_f16(a, wf[nt][kc], acc[nt], 0, 0, 0);
      if (dec) {   // fc: B row 0 = w_fc, rows 1..15 = 0 (zero-pad broadcast)
        const f16x8 wv = *reinterpret_cast<const f16x8*>(
            &wz[(lcol == 0) ? (kc * 32 + quad * 8) : 512]);
        accF = __builtin_amdgcn_mfma_f32_16x16x32_f16(a, wv, accF, 0, 0, 0);
      }
    }
  };
  auto tail = [&](f32x4* acc, f32x4& accF, float* xv, float* cstv,
                  int bX0, int t, _Float16* hnxt, bool dec) {
    if (dec) {   // xt = fc(h_t), redundant per block; preds stored by ub0/w0
#pragma unroll
      for (int r = 0; r < 4; ++r) xv[r] = __shfl(accF[r], quad * 16) + bfc;
      if (ub == 0 && wid == 0 && lcol == 0) {
        const int p = t - TENC;
#pragma unroll
        for (int r = 0; r < 4; ++r)
          out[(size_t)(bX0 + quad * 4 + r) * PRED + p] = accF[r] + bfc;
      }
    }
    if (t < STEPS) {
      const u64 tagnew = tag_of(t + 1);
#pragma unroll
      for (int r = 0; r < 4; ++r) {
        const float xt = xv[r];
        const float gi = acc[0][r] + xt * wih[0] + bias[0];
        const float gf = acc[1][r] + xt * wih[1] + bias[1];
        const float gg = acc[2][r] + xt * wih[2] + bias[2];
        const float go = acc[3][r] + xt * wih[3] + bias[3];
        const float si = 1.f / (1.f + __expf(-gi));
        const float sf = 1.f / (1.f + __expf(-gf));
        const float so = 1.f / (1.f + __expf(-go));
        const float tg = 1.f - 2.f / (1.f + __expf(2.f * gg));
        const float cn = sf * cstv[r] + si * tg;
        cstv[r] = cn;
        const float tc = 1.f - 2.f / (1.f + __expf(2.f * cn));
        const float hn = so * tc;

        const unsigned short hb = __builtin_bit_cast(unsigned short, (_Float16)hn);
        const unsigned v0  = hb;
        const unsigned o0  = (unsigned)__shfl_xor((int)v0, 1);
        const unsigned p01 = (lcol & 1) ? ((v0 << 16) | o0) : ((o0 << 16) | v0);
        const unsigned q   = (unsigned)__shfl_xor((int)p01, 2);
        u64 p4 = (lcol & 2) ? (((u64)p01 << 32) | (u64)q)
                            : (((u64)q << 32) | (u64)p01);
        p4 = (p4 & ~TAG_MASK) | tagnew;
        if ((lcol & 3) == r) {
          _Float16* dst = hnxt + (size_t)(bX0 + quad * 4 + r) * HDIM + uoff;
          __hip_atomic_store((u64*)dst, p4, __ATOMIC_RELAXED,
                             __HIP_MEMORY_SCOPE_AGENT);
        }
      }
    }
  };

  issue4(tA, hbuf + (size_t)bA0 * HDIM);   // prologue: A(0) + xA(0) in flight
#pragma unroll
  for (int r = 0; r < 4; ++r)
    xA[r] = loadx(x + (size_t)(bA0 + quad * 4 + r) * TENC + 0);

  for (int t = 0; t <= STEPS; ++t) {
    const _Float16* hcur = hbuf + (size_t)(t & 1) * BATCH * HDIM;
    _Float16*       hnxt = hbuf + (size_t)((t + 1) & 1) * BATCH * HDIM;
    const u64 expect = tag_of(t);
    const bool dec = (t >= TENC);

    // ================= phase A =================
    asm volatile("s_waitcnt vmcnt(0)" ::: "memory");   // tA + xA(t); tail-B(t-1) stores
    validate4(tA, hcur + (size_t)bA0 * HDIM, expect);
    stage4(tA, hsA);
    __syncthreads();
    issue4(tB, hcur + (size_t)bB0 * HDIM);             // B(t) flies during A compute
    if (!dec) {                                        // xB(t) flies during A compute
#pragma unroll
      for (int r = 0; r < 4; ++r)
        xB[r] = loadx(x + (size_t)(bB0 + quad * 4 + r) * TENC + t);
    }

    f32x4 accA[4], accFA;
#pragma unroll
    for (int nt = 0; nt < 4; ++nt) accA[nt] = (f32x4){0.f, 0.f, 0.f, 0.f};
    accFA = (f32x4){0.f, 0.f, 0.f, 0.f};
    gemm(hsA, accA, accFA, dec);
    tail(accA, accFA, xA, cstA, bA0, t, hnxt, dec);

    // ================= phase B =================
    asm volatile("s_waitcnt vmcnt(0)" ::: "memory");   // tB + xB(t); tail-A(t) stores
    validate4(tB, hcur + (size_t)bB0 * HDIM, expect);
    stage4(tB, hsB);
    __syncthreads();
    if (t < STEPS)
      issue4(tA, hnxt + (size_t)bA0 * HDIM);           // A(t+1) flies during B compute
    if (t + 1 < TENC) {                                // xA(t+1) flies during B compute
#pragma unroll
      for (int r = 0; r < 4; ++r)
        xA[r] = loadx(x + (size_t)(bA0 + quad * 4 + r) * TENC + t + 1);
    }

    f32x4 accB[4], accFB;
#pragma unroll
    for (int nt = 0; nt < 4; ++nt) accB[nt] = (f32x4){0.f, 0.f, 0.f, 0.f};
    accFB = (f32x4){0.f, 0.f, 0.f, 0.f};
    gemm(hsB, accB, accFB, dec);
    tail(accB, accFB, xB, cstB, bB0, t, hnxt, dec);
  }
}

extern "C" void kernel_launch(void* const* d_in, const int* in_sizes, int n_in,
                              void* d_out, int out_size, void* d_ws, size_t ws_size,
                              hipStream_t stream) {
  const float* x    = (const float*)d_in[0];
  const float* w_ih = (const float*)d_in[1];
  const float* w_hh = (const float*)d_in[2];
  const float* b_ih = (const float*)d_in[3];
  const float* b_hh = (const float*)d_in[4];
  const float* w_fc = (const float*)d_in[5];
  const float* b_fc = (const float*)d_in[6];
  float* out = (float*)d_out;
  _Float16* hbuf = (_Float16*)((char*)d_ws + HB_OFF);

  hipLaunchKernelGGL(init_kernel, dim3(256), dim3(256), 0, stream, (int*)d_ws);
  hipLaunchKernelGGL(lstm_persist, dim3(256), dim3(256), 0, stream,
                     x, w_ih, w_hh, b_ih, b_hh, w_fc, b_fc, out, hbuf);
}

// Round 6
// 3105.596 us; speedup vs baseline: 1.2778x; 1.1104x over previous
//
#include <hip/hip_runtime.h>

typedef _Float16 f16x8 __attribute__((ext_vector_type(8)));
typedef float    f32x4 __attribute__((ext_vector_type(4)));
typedef unsigned long long u64;
typedef u64 u64x2 __attribute__((ext_vector_type(2)));

constexpr int BATCH = 1024;
constexpr int HDIM  = 512;
constexpr int TENC  = 512;
constexpr int PRED  = 48;
constexpr int STEPS = TENC + PRED - 1;   // 559 cell steps; loop runs 560 (last = fc only)
constexpr int NG    = 64;                // groups (16 batches each)
constexpr int GB    = 16;                // batches per group = one MFMA m-tile
constexpr int UBU   = 64;                // units per block (4 waves x 16)
constexpr int HB_OFF = 32768;

// In-band tag (R7/R8-proven): each 4B dword of stored h carries step tag at
// bit0/bit16. h_t in buffer t&1, tag t&3; skew <= 1 step => ABA-safe.
// R16 theory: R0/R11/R15 all ~6.4us/step regardless of consumer polling
// style => the cost is PRODUCER-side: every phase started with vmcnt(0),
// which waits the previous tail's scattered 8B agent-scope h-stores (64
// partial-line transactions/wave) to ACK at the coherence point. Fix:
// (a) boundary waits become vmcnt(1) (h-store is always the NEWEST vmem op
//     of a phase; loads are older => vmcnt(1) waits all loads, leaves the
//     store in flight). Tag protocol already tolerates late stores.
// (b) __syncthreads() -> lgkmcnt(0) + raw s_barrier (else compiler emits
//     its own vmcnt(0) drain at the barrier).
// (c) h-stores made line-dense via a 2KB LDS repack: each wave store now
//     writes 4 full 128B row segments instead of 64 scattered 8B pieces.
constexpr u64 TAG_MASK = 0x0001000100010001ull;
__device__ __forceinline__ u64 tag_of(int t) {
  return ((u64)(t & 1) | ((u64)((t >> 1) & 1) << 16)) * 0x0000000100000001ull;
}

__global__ void init_kernel(int* wsi) {
  int idx = blockIdx.x * blockDim.x + threadIdx.x;
  int stride = gridDim.x * blockDim.x;
  const int nws = (HB_OFF + BATCH * HDIM * 2) / 4;  // hbuf[0] = h_0 = 0 (tag 00)
  for (int i = idx; i < nws; i += stride) wsi[i] = 0;
  // hbuf[1] stays 0xAA poison -> tag-invalid until written
}

static __device__ __forceinline__ f16x8 load16_llc(const _Float16* p) {
  f16x8 v;
  asm volatile("global_load_dwordx4 %0, %1, off sc0 sc1"
               : "=v"(v) : "v"((u64)p) : "memory");
  return v;
}
static __device__ __forceinline__ unsigned loadc_llc(const void* p) {
  unsigned v;   // 4B canary: in-band tag probe
  asm volatile("global_load_dword %0, %1, off sc0 sc1"
               : "=v"(v) : "v"((u64)p) : "memory");
  return v;
}
static __device__ __forceinline__ float loadx(const float* p) {
  float v;   // plain cached load via asm so compiler never vmcnt(0)-drains our prefetch
  asm volatile("global_load_dword %0, %1, off"
               : "=v"(v) : "v"((u64)p) : "memory");
  return v;
}
// s_sleep needs a literal operand: 4-step constant backoff ladder.
static __device__ __forceinline__ void sleep_bk(int stage) {
  if (stage == 0)      __builtin_amdgcn_s_sleep(1);
  else if (stage == 1) __builtin_amdgcn_s_sleep(2);
  else if (stage == 2) __builtin_amdgcn_s_sleep(4);
  else                 __builtin_amdgcn_s_sleep(8);
}
// raw barrier: LDS-drain + s_barrier, NO vmcnt drain (stores stay in flight)
static __device__ __forceinline__ void lds_barrier() {
  asm volatile("s_waitcnt lgkmcnt(0)" ::: "memory");
  __builtin_amdgcn_s_barrier();
}

// Two interleaved 16-batch recurrences per block (A: grp=bid>>3, B: grp+32),
// same 64-unit weight tile for both. Phase pipeline: B's remote loads fly
// during A's GEMM+epilogue and vice versa.
__global__ __launch_bounds__(256, 1) void lstm_persist(
    const float* __restrict__ x,
    const float* __restrict__ w_ih,
    const float* __restrict__ w_hh,
    const float* __restrict__ b_ih,
    const float* __restrict__ b_hh,
    const float* __restrict__ w_fc,
    const float* __restrict__ b_fc,
    float* __restrict__ out,          // [1024][48] fp32, plain stores
    _Float16* __restrict__ hbuf)      // [2][1024][512] fp16 ping-pong, tagged
{
  const int bid  = blockIdx.x;
  const int gA   = bid >> 3;          // group A (0..31); B = gA+32
  const int ub   = bid & 7;
  const int tid  = threadIdx.x;
  const int wid  = tid >> 6;
  const int lane = tid & 63;
  const int quad = lane >> 4;
  const int lcol = lane & 15;
  const int bA0  = gA * GB;
  const int bB0  = bA0 + NG / 2 * GB; // = bA0 + 512
  const int myu  = ub * UBU + wid * 16 + lcol;

  __shared__ __align__(16) _Float16 hsA[GB][520];    // 16.6 KB
  __shared__ __align__(16) _Float16 hsB[GB][520];    // 16.6 KB
  __shared__ __align__(16) _Float16 wz[520];         // fp16 w_fc + zero pad
  __shared__ __align__(16) _Float16 rp[GB][UBU];     // 2 KB h-store repack

  for (int k = tid; k < 512; k += 256) wz[k] = (_Float16)w_fc[k];
  if (tid < 8) wz[512 + tid] = (_Float16)0.f;

  // ---- full-K weight B-frags (n=lcol, k=kc*32+quad*8+j) ----
  f16x8 wf[4][16];
  float wih[4], bias[4];
#pragma unroll
  for (int nt = 0; nt < 4; ++nt) {
    const int j = nt * HDIM + myu;
    wih[nt]  = w_ih[j];
    bias[nt] = b_ih[j] + b_hh[j];
#pragma unroll
    for (int kc = 0; kc < 16; ++kc) {
      const float* s = w_hh + (size_t)j * HDIM + kc * 32 + quad * 8;
      f16x8 v;
#pragma unroll
      for (int i = 0; i < 8; ++i) v[i] = (_Float16)s[i];
      wf[nt][kc] = v;
    }
  }
  const float bfc = b_fc[0];

  float cstA[4], cstB[4];
#pragma unroll
  for (int r = 0; r < 4; ++r) { cstA[r] = 0.f; cstB[r] = 0.f; }

  // staging: 16 rows x 512 units = 1024 16B-chunks; thread covers 4
  // (c = i*256+tid: row=c>>6, col16=c&63). Includes own slice (tag
  // protocol covers own store->load reordering).
  f16x8 tA[4], tB[4];
  float xA[4], xB[4];

  auto issue4 = [&](f16x8* tr, const _Float16* base) {
#pragma unroll
    for (int i = 0; i < 4; ++i) {
      const int c = i * 256 + tid;
      tr[i] = load16_llc(base + (size_t)(c >> 6) * HDIM + (c & 63) * 8);
    }
  };
  // canary validate (R15-proven): on staleness poll 4B/chunk with constant
  // sleep ladder; full 16B reload once the canary tag flips; full re-check
  // clears the chunk. Internal vmcnt(0) only on the stale path.
  auto validate4 = [&](f16x8* tr, const _Float16* base, u64 expect) {
    const unsigned exp32 = (unsigned)expect & 0x00010001u;
    unsigned stale = 0;
#pragma unroll
    for (int i = 0; i < 4; ++i) {
      u64x2 w2 = __builtin_bit_cast(u64x2, tr[i]);
      if (((w2[0] & TAG_MASK) != expect) || ((w2[1] & TAG_MASK) != expect))
        stale |= 1u << i;
    }
    int slp = 0;
    while (stale) {
      sleep_bk(slp);
      if (slp < 3) ++slp;
      unsigned cv[4];
#pragma unroll
      for (int i = 0; i < 4; ++i)
        if (stale & (1u << i)) {
          const int c = i * 256 + tid;
          cv[i] = loadc_llc(base + (size_t)(c >> 6) * HDIM + (c & 63) * 8);
        }
      asm volatile("s_waitcnt vmcnt(0)" ::: "memory");
      unsigned rdy = 0;
#pragma unroll
      for (int i = 0; i < 4; ++i)
        if ((stale & (1u << i)) && ((cv[i] & 0x00010001u) == exp32))
          rdy |= 1u << i;
      if (!rdy) continue;
#pragma unroll
      for (int i = 0; i < 4; ++i)
        if (rdy & (1u << i)) {
          const int c = i * 256 + tid;
          tr[i] = load16_llc(base + (size_t)(c >> 6) * HDIM + (c & 63) * 8);
        }
      asm volatile("s_waitcnt vmcnt(0)" ::: "memory");
#pragma unroll
      for (int i = 0; i < 4; ++i)
        if (rdy & (1u << i)) {
          u64x2 w2 = __builtin_bit_cast(u64x2, tr[i]);
          if (((w2[0] & TAG_MASK) == expect) && ((w2[1] & TAG_MASK) == expect))
            stale &= ~(1u << i);
        }
    }
  };
  auto stage4 = [&](f16x8* tr, _Float16 (*hsp)[520]) {
#pragma unroll
    for (int i = 0; i < 4; ++i) {
      const int c = i * 256 + tid;
      *reinterpret_cast<f16x8*>(&hsp[c >> 6][(c & 63) * 8]) = tr[i];
    }
  };
  auto gemm = [&](const _Float16 (*hsp)[520], f32x4* acc, f32x4& accF, bool dec) {
#pragma unroll
    for (int kc = 0; kc < 16; ++kc) {
      const f16x8 a = *reinterpret_cast<const f16x8*>(&hsp[lcol][kc * 32 + quad * 8]);
#pragma unroll
      for (int nt = 0; nt < 4; ++nt)
        acc[nt] = __builtin_amdgcn_mfma_f32_16x16x32_f16(a, wf[nt][kc], acc[nt], 0, 0, 0);
      if (dec) {   // fc: B row 0 = w_fc, rows 1..15 = 0 (zero-pad broadcast)
        const f16x8 wv = *reinterpret_cast<const f16x8*>(
            &wz[(lcol == 0) ? (kc * 32 + quad * 8) : 512]);
        accF = __builtin_amdgcn_mfma_f32_16x16x32_f16(a, wv, accF, 0, 0, 0);
      }
    }
  };
  // tail: cell epilogue. h written to rp (LDS), then block-wide line-dense
  // store: thread tid stores 8B at row tid>>4, units (tid&15)*4 -> per wave
  // instruction 4 FULL 128B row segments (was: 64 scattered 8B pieces).
  // The h-store is the LAST vmem op of the phase (vmcnt(1) discipline).
  auto tail = [&](f32x4* acc, f32x4& accF, float* xv, float* cstv,
                  int bX0, int t, _Float16* hnxt, bool dec) {
    if (dec) {   // xt = fc(h_t), redundant per block; preds stored by ub0/w0
#pragma unroll
      for (int r = 0; r < 4; ++r) xv[r] = __shfl(accF[r], quad * 16) + bfc;
      if (ub == 0 && wid == 0 && lcol == 0) {
        const int p = t - TENC;
#pragma unroll
        for (int r = 0; r < 4; ++r)
          out[(size_t)(bX0 + quad * 4 + r) * PRED + p] = accF[r] + bfc;
      }
    }
    if (t < STEPS) {
      const u64 tagnew = tag_of(t + 1);
#pragma unroll
      for (int r = 0; r < 4; ++r) {
        const float xt = xv[r];
        const float gi = acc[0][r] + xt * wih[0] + bias[0];
        const float gf = acc[1][r] + xt * wih[1] + bias[1];
        const float gg = acc[2][r] + xt * wih[2] + bias[2];
        const float go = acc[3][r] + xt * wih[3] + bias[3];
        const float si = 1.f / (1.f + __expf(-gi));
        const float sf = 1.f / (1.f + __expf(-gf));
        const float so = 1.f / (1.f + __expf(-go));
        const float tg = 1.f - 2.f / (1.f + __expf(2.f * gg));
        const float cn = sf * cstv[r] + si * tg;
        cstv[r] = cn;
        const float tc = 1.f - 2.f / (1.f + __expf(2.f * cn));
        rp[quad * 4 + r][wid * 16 + lcol] = (_Float16)(so * tc);
      }
      lds_barrier();
      const u64 hv = *reinterpret_cast<const u64*>(&rp[tid >> 4][(tid & 15) * 4]);
      const u64 p4 = (hv & ~TAG_MASK) | tagnew;
      _Float16* dst = hnxt + (size_t)(bX0 + (tid >> 4)) * HDIM
                      + ub * UBU + (tid & 15) * 4;
      __hip_atomic_store((u64*)dst, p4, __ATOMIC_RELAXED,
                         __HIP_MEMORY_SCOPE_AGENT);
    }
  };

  issue4(tA, hbuf + (size_t)bA0 * HDIM);   // prologue: A(0) + xA(0) in flight
#pragma unroll
  for (int r = 0; r < 4; ++r)
    xA[r] = loadx(x + (size_t)(bA0 + quad * 4 + r) * TENC + 0);

  for (int t = 0; t <= STEPS; ++t) {
    const _Float16* hcur = hbuf + (size_t)(t & 1) * BATCH * HDIM;
    _Float16*       hnxt = hbuf + (size_t)((t + 1) & 1) * BATCH * HDIM;
    const u64 expect = tag_of(t);
    const bool dec = (t >= TENC);

    // ================= phase A =================
    // vmcnt(1): wait the 4-8 loads (older), leave the newest op (previous
    // tail's h-store) in flight. t==0 has no preceding store -> full drain.
    if (t == 0) { asm volatile("s_waitcnt vmcnt(0)" ::: "memory"); }
    else        { asm volatile("s_waitcnt vmcnt(1)" ::: "memory"); }
    validate4(tA, hcur + (size_t)bA0 * HDIM, expect);
    stage4(tA, hsA);
    lds_barrier();
    issue4(tB, hcur + (size_t)bB0 * HDIM);             // B(t) flies during A compute
    if (!dec) {                                        // xB(t) flies during A compute
#pragma unroll
      for (int r = 0; r < 4; ++r)
        xB[r] = loadx(x + (size_t)(bB0 + quad * 4 + r) * TENC + t);
    }

    f32x4 accA[4], accFA;
#pragma unroll
    for (int nt = 0; nt < 4; ++nt) accA[nt] = (f32x4){0.f, 0.f, 0.f, 0.f};
    accFA = (f32x4){0.f, 0.f, 0.f, 0.f};
    gemm(hsA, accA, accFA, dec);
    tail(accA, accFA, xA, cstA, bA0, t, hnxt, dec);

    // ================= phase B =================
    asm volatile("s_waitcnt vmcnt(1)" ::: "memory");   // tB + xB landed; h-store flies
    validate4(tB, hcur + (size_t)bB0 * HDIM, expect);
    stage4(tB, hsB);
    lds_barrier();
    if (t < STEPS)
      issue4(tA, hnxt + (size_t)bA0 * HDIM);           // A(t+1) flies during B compute
    if (t + 1 < TENC) {                                // xA(t+1) flies during B compute
#pragma unroll
      for (int r = 0; r < 4; ++r)
        xA[r] = loadx(x + (size_t)(bA0 + quad * 4 + r) * TENC + t + 1);
    }

    f32x4 accB[4], accFB;
#pragma unroll
    for (int nt = 0; nt < 4; ++nt) accB[nt] = (f32x4){0.f, 0.f, 0.f, 0.f};
    accFB = (f32x4){0.f, 0.f, 0.f, 0.f};
    gemm(hsB, accB, accFB, dec);
    tail(accB, accFB, xB, cstB, bB0, t, hnxt, dec);
  }
}

extern "C" void kernel_launch(void* const* d_in, const int* in_sizes, int n_in,
                              void* d_out, int out_size, void* d_ws, size_t ws_size,
                              hipStream_t stream) {
  const float* x    = (const float*)d_in[0];
  const float* w_ih = (const float*)d_in[1];
  const float* w_hh = (const float*)d_in[2];
  const float* b_ih = (const float*)d_in[3];
  const float* b_hh = (const float*)d_in[4];
  const float* w_fc = (const float*)d_in[5];
  const float* b_fc = (const float*)d_in[6];
  float* out = (float*)d_out;
  _Float16* hbuf = (_Float16*)((char*)d_ws + HB_OFF);

  hipLaunchKernelGGL(init_kernel, dim3(256), dim3(256), 0, stream, (int*)d_ws);
  hipLaunchKernelGGL(lstm_persist, dim3(256), dim3(256), 0, stream,
                     x, w_ih, w_hh, b_ih, b_hh, w_fc, b_fc, out, hbuf);
}

// Round 8
// 2956.469 us; speedup vs baseline: 1.3423x; 1.0504x over previous
//
#include <hip/hip_runtime.h>

typedef _Float16 f16x8 __attribute__((ext_vector_type(8)));
typedef float    f32x4 __attribute__((ext_vector_type(4)));
typedef unsigned long long u64;
typedef u64 u64x2 __attribute__((ext_vector_type(2)));

constexpr int BATCH = 1024;
constexpr int HDIM  = 512;
constexpr int TENC  = 512;
constexpr int PRED  = 48;
constexpr int STEPS = TENC + PRED - 1;   // 559 cell steps; loop runs 560 (last = fc only)
constexpr int NG    = 64;                // groups (16 batches each)
constexpr int GB    = 16;                // batches per group = one MFMA m-tile
constexpr int UBU   = 64;                // units per block (4 waves x 16)
constexpr int HB_OFF = 32768;

// R18 = R16 + sched_barrier(0) fences (rule #18, m214 r263/r282): hipcc may
// hoist register-only ops (our tag/canary checks on asm-load outputs) PAST
// inline-asm s_waitcnt despite the "memory" clobber -- the check data-depends
// on the LOAD asm, not the WAIT asm. Hoisted checks read pre-load VGPR
// contents (previous step's data) -> always-stale -> stale path's vmcnt(0)
// full drain every phase (the persistent ~5us/step), and in some builds the
// hoisted CANARY check never freshens -> infinite loop -> watchdog abort
// (R13/R17 failure signature). The fence after every s_waitcnt pins the
// checks after the waits. Everything else identical to R16 (3105us proven):
// in-band tags, vmcnt(1) boundaries, raw lds_barrier, line-dense h-stores.
constexpr u64 TAG_MASK = 0x0001000100010001ull;
__device__ __forceinline__ u64 tag_of(int t) {
  return ((u64)(t & 1) | ((u64)((t >> 1) & 1) << 16)) * 0x0000000100000001ull;
}

__global__ void init_kernel(int* wsi) {
  int idx = blockIdx.x * blockDim.x + threadIdx.x;
  int stride = gridDim.x * blockDim.x;
  const int nws = (HB_OFF + BATCH * HDIM * 2) / 4;  // hbuf[0] = h_0 = 0 (tag 00)
  for (int i = idx; i < nws; i += stride) wsi[i] = 0;
  // hbuf[1] stays 0xAA poison -> tag-invalid until written
}

static __device__ __forceinline__ f16x8 load16_llc(const _Float16* p) {
  f16x8 v;
  asm volatile("global_load_dwordx4 %0, %1, off sc0 sc1"
               : "=v"(v) : "v"((u64)p) : "memory");
  return v;
}
static __device__ __forceinline__ unsigned loadc_llc(const void* p) {
  unsigned v;   // 4B canary: in-band tag probe
  asm volatile("global_load_dword %0, %1, off sc0 sc1"
               : "=v"(v) : "v"((u64)p) : "memory");
  return v;
}
static __device__ __forceinline__ float loadx(const float* p) {
  float v;   // plain cached load via asm so compiler never drains our pipeline
  asm volatile("global_load_dword %0, %1, off"
               : "=v"(v) : "v"((u64)p) : "memory");
  return v;
}
// s_sleep needs a literal operand: 4-step constant backoff ladder.
static __device__ __forceinline__ void sleep_bk(int stage) {
  if (stage == 0)      __builtin_amdgcn_s_sleep(1);
  else if (stage == 1) __builtin_amdgcn_s_sleep(2);
  else if (stage == 2) __builtin_amdgcn_s_sleep(4);
  else                 __builtin_amdgcn_s_sleep(8);
}
// waitcnt + scheduling fence: checks that gate on this wait MUST NOT hoist
// above it (rule #18). The fence is the documented fix.
static __device__ __forceinline__ void wait_vm0_fenced() {
  asm volatile("s_waitcnt vmcnt(0)" ::: "memory");
  __builtin_amdgcn_sched_barrier(0);
}
static __device__ __forceinline__ void wait_vm1_fenced() {
  asm volatile("s_waitcnt vmcnt(1)" ::: "memory");
  __builtin_amdgcn_sched_barrier(0);
}
// raw barrier: LDS-drain + s_barrier, NO vmcnt drain (stores/loads in flight)
static __device__ __forceinline__ void lds_barrier() {
  asm volatile("s_waitcnt lgkmcnt(0)" ::: "memory");
  __builtin_amdgcn_s_barrier();
}

// Two interleaved 16-batch recurrences per block (A: grp=bid>>3, B: grp+32),
// same 64-unit weight tile for both. Phase pipeline: B's remote loads fly
// during A's GEMM+epilogue and vice versa.
__global__ __launch_bounds__(256, 1) void lstm_persist(
    const float* __restrict__ x,
    const float* __restrict__ w_ih,
    const float* __restrict__ w_hh,
    const float* __restrict__ b_ih,
    const float* __restrict__ b_hh,
    const float* __restrict__ w_fc,
    const float* __restrict__ b_fc,
    float* __restrict__ out,          // [1024][48] fp32, plain stores
    _Float16* __restrict__ hbuf)      // [2][1024][512] fp16 ping-pong, tagged
{
  const int bid  = blockIdx.x;
  const int gA   = bid >> 3;          // group A (0..31); B = gA+32
  const int ub   = bid & 7;
  const int tid  = threadIdx.x;
  const int wid  = tid >> 6;
  const int lane = tid & 63;
  const int quad = lane >> 4;
  const int lcol = lane & 15;
  const int bA0  = gA * GB;
  const int bB0  = bA0 + NG / 2 * GB; // = bA0 + 512
  const int myu  = ub * UBU + wid * 16 + lcol;

  __shared__ __align__(16) _Float16 hsA[GB][520];    // 16.6 KB
  __shared__ __align__(16) _Float16 hsB[GB][520];    // 16.6 KB
  __shared__ __align__(16) _Float16 wz[520];         // fp16 w_fc + zero pad
  __shared__ __align__(16) _Float16 rp[GB][UBU];     // 2 KB h-store repack

  for (int k = tid; k < 512; k += 256) wz[k] = (_Float16)w_fc[k];
  if (tid < 8) wz[512 + tid] = (_Float16)0.f;

  // ---- full-K weight B-frags (n=lcol, k=kc*32+quad*8+j) ----
  f16x8 wf[4][16];
  float wih[4], bias[4];
#pragma unroll
  for (int nt = 0; nt < 4; ++nt) {
    const int j = nt * HDIM + myu;
    wih[nt]  = w_ih[j];
    bias[nt] = b_ih[j] + b_hh[j];
#pragma unroll
    for (int kc = 0; kc < 16; ++kc) {
      const float* s = w_hh + (size_t)j * HDIM + kc * 32 + quad * 8;
      f16x8 v;
#pragma unroll
      for (int i = 0; i < 8; ++i) v[i] = (_Float16)s[i];
      wf[nt][kc] = v;
    }
  }
  const float bfc = b_fc[0];

  float cstA[4], cstB[4];
#pragma unroll
  for (int r = 0; r < 4; ++r) { cstA[r] = 0.f; cstB[r] = 0.f; }

  // staging: 16 rows x 512 units = 1024 16B-chunks; thread covers 4
  // (c = i*256+tid: row=c>>6, col16=c&63). Includes own slice (tag
  // protocol covers own store->load reordering).
  f16x8 tA[4], tB[4];
  float xA[4], xB[4];

  auto issue4 = [&](f16x8* tr, const _Float16* base) {
#pragma unroll
    for (int i = 0; i < 4; ++i) {
      const int c = i * 256 + tid;
      tr[i] = load16_llc(base + (size_t)(c >> 6) * HDIM + (c & 63) * 8);
    }
  };
  // canary validate: stale path polls 4B/chunk with sleep ladder; 16B reload
  // once canary tag flips; re-check clears chunk. Every check is fenced
  // behind its wait (R18).
  auto validate4 = [&](f16x8* tr, const _Float16* base, u64 expect) {
    const unsigned exp32 = (unsigned)expect & 0x00010001u;
    unsigned stale = 0;
#pragma unroll
    for (int i = 0; i < 4; ++i) {
      u64x2 w2 = __builtin_bit_cast(u64x2, tr[i]);
      if (((w2[0] & TAG_MASK) != expect) || ((w2[1] & TAG_MASK) != expect))
        stale |= 1u << i;
    }
    int slp = 0;
    while (stale) {
      sleep_bk(slp);
      if (slp < 3) ++slp;
      unsigned cv[4];
#pragma unroll
      for (int i = 0; i < 4; ++i)
        if (stale & (1u << i)) {
          const int c = i * 256 + tid;
          cv[i] = loadc_llc(base + (size_t)(c >> 6) * HDIM + (c & 63) * 8);
        }
      wait_vm0_fenced();          // canary values readable only after this
      unsigned rdy = 0;
#pragma unroll
      for (int i = 0; i < 4; ++i)
        if ((stale & (1u << i)) && ((cv[i] & 0x00010001u) == exp32))
          rdy |= 1u << i;
      if (!rdy) continue;
#pragma unroll
      for (int i = 0; i < 4; ++i)
        if (rdy & (1u << i)) {
          const int c = i * 256 + tid;
          tr[i] = load16_llc(base + (size_t)(c >> 6) * HDIM + (c & 63) * 8);
        }
      wait_vm0_fenced();          // reloads readable only after this
#pragma unroll
      for (int i = 0; i < 4; ++i)
        if (rdy & (1u << i)) {
          u64x2 w2 = __builtin_bit_cast(u64x2, tr[i]);
          if (((w2[0] & TAG_MASK) == expect) && ((w2[1] & TAG_MASK) == expect))
            stale &= ~(1u << i);
        }
    }
  };
  auto stage4 = [&](f16x8* tr, _Float16 (*hsp)[520]) {
#pragma unroll
    for (int i = 0; i < 4; ++i) {
      const int c = i * 256 + tid;
      *reinterpret_cast<f16x8*>(&hsp[c >> 6][(c & 63) * 8]) = tr[i];
    }
  };
  auto gemm = [&](const _Float16 (*hsp)[520], f32x4* acc, f32x4& accF, bool dec) {
#pragma unroll
    for (int kc = 0; kc < 16; ++kc) {
      const f16x8 a = *reinterpret_cast<const f16x8*>(&hsp[lcol][kc * 32 + quad * 8]);
#pragma unroll
      for (int nt = 0; nt < 4; ++nt)
        acc[nt] = __builtin_amdgcn_mfma_f32_16x16x32_f16(a, wf[nt][kc], acc[nt], 0, 0, 0);
      if (dec) {   // fc: B row 0 = w_fc, rows 1..15 = 0 (zero-pad broadcast)
        const f16x8 wv = *reinterpret_cast<const f16x8*>(
            &wz[(lcol == 0) ? (kc * 32 + quad * 8) : 512]);
        accF = __builtin_amdgcn_mfma_f32_16x16x32_f16(a, wv, accF, 0, 0, 0);
      }
    }
  };
  // tail: cell epilogue. h written to rp (LDS), then block-wide line-dense
  // store: thread tid stores 8B at row tid>>4, units (tid&15)*4 -> per wave
  // instruction 4 FULL 128B row segments. h-store is the LAST vmem op of
  // the phase (vmcnt(1) discipline).
  auto tail = [&](f32x4* acc, f32x4& accF, float* xv, float* cstv,
                  int bX0, int t, _Float16* hnxt, bool dec) {
    if (dec) {   // xt = fc(h_t), redundant per block; preds stored by ub0/w0
#pragma unroll
      for (int r = 0; r < 4; ++r) xv[r] = __shfl(accF[r], quad * 16) + bfc;
      if (ub == 0 && wid == 0 && lcol == 0) {
        const int p = t - TENC;
#pragma unroll
        for (int r = 0; r < 4; ++r)
          out[(size_t)(bX0 + quad * 4 + r) * PRED + p] = accF[r] + bfc;
      }
    }
    if (t < STEPS) {
      const u64 tagnew = tag_of(t + 1);
#pragma unroll
      for (int r = 0; r < 4; ++r) {
        const float xt = xv[r];
        const float gi = acc[0][r] + xt * wih[0] + bias[0];
        const float gf = acc[1][r] + xt * wih[1] + bias[1];
        const float gg = acc[2][r] + xt * wih[2] + bias[2];
        const float go = acc[3][r] + xt * wih[3] + bias[3];
        const float si = 1.f / (1.f + __expf(-gi));
        const float sf = 1.f / (1.f + __expf(-gf));
        const float so = 1.f / (1.f + __expf(-go));
        const float tg = 1.f - 2.f / (1.f + __expf(2.f * gg));
        const float cn = sf * cstv[r] + si * tg;
        cstv[r] = cn;
        const float tc = 1.f - 2.f / (1.f + __expf(2.f * cn));
        rp[quad * 4 + r][wid * 16 + lcol] = (_Float16)(so * tc);
      }
      lds_barrier();
      const u64 hv = *reinterpret_cast<const u64*>(&rp[tid >> 4][(tid & 15) * 4]);
      const u64 p4 = (hv & ~TAG_MASK) | tagnew;
      _Float16* dst = hnxt + (size_t)(bX0 + (tid >> 4)) * HDIM
                      + ub * UBU + (tid & 15) * 4;
      __hip_atomic_store((u64*)dst, p4, __ATOMIC_RELAXED,
                         __HIP_MEMORY_SCOPE_AGENT);
    }
  };

  issue4(tA, hbuf + (size_t)bA0 * HDIM);   // prologue: A(0) + xA(0) in flight
#pragma unroll
  for (int r = 0; r < 4; ++r)
    xA[r] = loadx(x + (size_t)(bA0 + quad * 4 + r) * TENC + 0);

  for (int t = 0; t <= STEPS; ++t) {
    const _Float16* hcur = hbuf + (size_t)(t & 1) * BATCH * HDIM;
    _Float16*       hnxt = hbuf + (size_t)((t + 1) & 1) * BATCH * HDIM;
    const u64 expect = tag_of(t);
    const bool dec = (t >= TENC);

    // ================= phase A =================
    // vmcnt(1): wait the loads (older), leave the newest op (previous
    // tail's h-store) in flight. t==0 has no preceding store -> full drain.
    if (t == 0) wait_vm0_fenced();
    else        wait_vm1_fenced();
    validate4(tA, hcur + (size_t)bA0 * HDIM, expect);
    stage4(tA, hsA);
    lds_barrier();
    issue4(tB, hcur + (size_t)bB0 * HDIM);             // B(t) flies during A compute
    if (!dec) {                                        // xB(t) flies during A compute
#pragma unroll
      for (int r = 0; r < 4; ++r)
        xB[r] = loadx(x + (size_t)(bB0 + quad * 4 + r) * TENC + t);
    }

    f32x4 accA[4], accFA;
#pragma unroll
    for (int nt = 0; nt < 4; ++nt) accA[nt] = (f32x4){0.f, 0.f, 0.f, 0.f};
    accFA = (f32x4){0.f, 0.f, 0.f, 0.f};
    gemm(hsA, accA, accFA, dec);
    tail(accA, accFA, xA, cstA, bA0, t, hnxt, dec);

    // ================= phase B =================
    wait_vm1_fenced();                                 // tB + xB landed; h-store flies
    validate4(tB, hcur + (size_t)bB0 * HDIM, expect);
    stage4(tB, hsB);
    lds_barrier();
    if (t < STEPS)
      issue4(tA, hnxt + (size_t)bA0 * HDIM);           // A(t+1) flies during B compute
    if (t + 1 < TENC) {                                // xA(t+1) flies during B compute
#pragma unroll
      for (int r = 0; r < 4; ++r)
        xA[r] = loadx(x + (size_t)(bA0 + quad * 4 + r) * TENC + t + 1);
    }

    f32x4 accB[4], accFB;
#pragma unroll
    for (int nt = 0; nt < 4; ++nt) accB[nt] = (f32x4){0.f, 0.f, 0.f, 0.f};
    accFB = (f32x4){0.f, 0.f, 0.f, 0.f};
    gemm(hsB, accB, accFB, dec);
    tail(accB, accFB, xB, cstB, bB0, t, hnxt, dec);
  }
}

extern "C" void kernel_launch(void* const* d_in, const int* in_sizes, int n_in,
                              void* d_out, int out_size, void* d_ws, size_t ws_size,
                              hipStream_t stream) {
  const float* x    = (const float*)d_in[0];
  const float* w_ih = (const float*)d_in[1];
  const float* w_hh = (const float*)d_in[2];
  const float* b_ih = (const float*)d_in[3];
  const float* b_hh = (const float*)d_in[4];
  const float* w_fc = (const float*)d_in[5];
  const float* b_fc = (const float*)d_in[6];
  float* out = (float*)d_out;
  _Float16* hbuf = (_Float16*)((char*)d_ws + HB_OFF);

  hipLaunchKernelGGL(init_kernel, dim3(256), dim3(256), 0, stream, (int*)d_ws);
  hipLaunchKernelGGL(lstm_persist, dim3(256), dim3(256), 0, stream,
                     x, w_ih, w_hh, b_ih, b_hh, w_fc, b_fc, out, hbuf);
}